// Round 5
// baseline (292.733 us; speedup 1.0000x reference)
//
#include <hip/hip_runtime.h>
#include <math.h>

// ---------------------------------------------------------------------------
// GAT x2 + linear + log_softmax on MI355X. R16.
//   - R15 (slotted-ebuf CSR build, verified: fused 50us / WRITE 22MB) kept.
//   - gat_agg restructured 4x16xbf16x4 -> 8x8xbf16x8:
//     * 1 load instr per edge per 8-lane group (half the loads + addr calc)
//     * 2 shfl per 8 edges (was 8 per 16)
//     * round granularity 8 edges -> padding waste 47% -> ~20% @ mean deg 17
//     * cross-group reduce now 3 shfl_xor levels (d=8,16,32), once per node.
//   - Everything else unchanged.
// ---------------------------------------------------------------------------

#define NEG_SLOPE 0.2f
#define NEG_BIG -3.0e38f

#define BSHIFT 9
#define BSIZE 512            // nodes per bucket
#define CEPB 8192            // edges per chunk block
#define ECAP 112             // ebuf records per (bucket,chunk) slot
#define CBPAD 256            // blockHist row stride

typedef __bf16 bf16x8 __attribute__((ext_vector_type(8)));
typedef __bf16 bf16x4 __attribute__((ext_vector_type(4)));
typedef float f32x4 __attribute__((ext_vector_type(4)));

__device__ __forceinline__ float lrelu(float x) {
    return x >= 0.f ? x : NEG_SLOPE * x;
}

__device__ __forceinline__ int wave_incl_scan(int v, int lane) {
#pragma unroll
    for (int d = 1; d < 64; d <<= 1) {
        int t = __shfl_up(v, d, 64);
        if (lane >= d) v += t;
    }
    return v;
}

// ---------------- fused: hist+place || gemm1 (K=128, fp32 A hi/lo) ---------

__global__ __launch_bounds__(256) void fused_hist_gemm(
        const int* __restrict__ src, const int* __restrict__ dst,
        int* __restrict__ bucketCount, int* __restrict__ blockHist,
        unsigned* __restrict__ ebuf, int E, int CB,
        const float* __restrict__ X, const float* __restrict__ W,
        const float* __restrict__ a_src, const float* __restrict__ a_dst,
        __bf16* __restrict__ Hout, float* __restrict__ as_, float* __restrict__ ad_,
        int N, int nTiles) {
    constexpr int K = 128;
    __shared__ __bf16 Whi[64][K + 8];
    __shared__ __bf16 Wlo[64][K + 8];
    __shared__ int hist[256];

    if (blockIdx.x < (unsigned)CB) {
        // ---- hist+place path: LDS rank capture, direct slotted ebuf write --
        const int t = threadIdx.x;
        hist[t] = 0;
        __syncthreads();
        const int c = blockIdx.x;
        const int e0 = c * CEPB;
        const int e1 = min(e0 + CEPB, E);
        int rr[CEPB / 256];
#pragma unroll
        for (int i = 0; i < CEPB / 256; ++i) {
            int e = e0 + i * 256 + t;
            if (e < e1) rr[i] = atomicAdd(&hist[dst[e] >> BSHIFT], 1);
        }
        __syncthreads();
        int hv = hist[t];
        blockHist[t * CBPAD + c] = hv;                    // plain store
        if (hv > 0) atomicAdd(&bucketCount[t], hv);       // fire-and-forget
#pragma unroll
        for (int i = 0; i < CEPB / 256; ++i) {
            int e = e0 + i * 256 + t;
            if (e < e1) {
                int d = dst[e];                            // L1/L2 hot
                int b = d >> BSHIFT;
                ebuf[((size_t)b * CB + c) * ECAP + rr[i]] =
                    ((unsigned)src[e] << BSHIFT) | (unsigned)(d & (BSIZE - 1));
            }
        }
        return;
    }

    // ---- gemm path ----
    const int gbid = blockIdx.x - CB;
    for (int idx = threadIdx.x; idx < K * 64; idx += 256) {
        int k = idx >> 6, n = idx & 63;
        float w = W[idx];
        __bf16 hi = (__bf16)w;
        Whi[n][k] = hi;
        Wlo[n][k] = (__bf16)(w - (float)hi);
    }
    __syncthreads();

    const int lane  = threadIdx.x & 63;
    const int wave  = threadIdx.x >> 6;
    const int row16 = lane & 15;
    const int quad  = lane >> 4;

    float asv[4], adv[4];
#pragma unroll
    for (int t = 0; t < 4; ++t) {
        asv[t] = a_src[t * 16 + row16];
        adv[t] = a_dst[t * 16 + row16];
    }

    for (int tile = gbid; tile < nTiles; tile += 1024) {
        const int nbase = tile * 64;
        int gn = nbase + wave * 16 + row16;
        if (gn >= N) gn = N - 1;
        const float* __restrict__ xp = X + (size_t)gn * K + quad * 8;

        float4 xv[K / 16];
#pragma unroll
        for (int c = 0; c < K / 32; ++c) {
            xv[2 * c]     = *(const float4*)(xp + c * 32);
            xv[2 * c + 1] = *(const float4*)(xp + c * 32 + 4);
        }

        f32x4 acc[4] = {{0.f, 0.f, 0.f, 0.f}, {0.f, 0.f, 0.f, 0.f},
                        {0.f, 0.f, 0.f, 0.f}, {0.f, 0.f, 0.f, 0.f}};
#pragma unroll
        for (int kc = 0; kc < K; kc += 32) {
            float xs[8];
            *(float4*)&xs[0] = xv[kc / 16];
            *(float4*)&xs[4] = xv[kc / 16 + 1];
            bf16x8 ahi, alo;
#pragma unroll
            for (int j = 0; j < 8; ++j) {
                __bf16 hi = (__bf16)xs[j];
                ahi[j] = hi;
                alo[j] = (__bf16)(xs[j] - (float)hi);
            }
#pragma unroll
            for (int t = 0; t < 4; ++t) {
                bf16x8 bhi = *(const bf16x8*)&Whi[t * 16 + row16][kc + quad * 8];
                bf16x8 blo = *(const bf16x8*)&Wlo[t * 16 + row16][kc + quad * 8];
                acc[t] = __builtin_amdgcn_mfma_f32_16x16x32_bf16(ahi, bhi, acc[t], 0, 0, 0);
                acc[t] = __builtin_amdgcn_mfma_f32_16x16x32_bf16(ahi, blo, acc[t], 0, 0, 0);
                acc[t] = __builtin_amdgcn_mfma_f32_16x16x32_bf16(alo, bhi, acc[t], 0, 0, 0);
            }
        }

        float ps[4] = {0.f, 0.f, 0.f, 0.f};
        float pd[4] = {0.f, 0.f, 0.f, 0.f};
#pragma unroll
        for (int t = 0; t < 4; ++t) {
#pragma unroll
            for (int r = 0; r < 4; ++r) {
                int gm = nbase + wave * 16 + quad * 4 + r;
                if (gm < N) Hout[(size_t)gm * 64 + t * 16 + row16] = (__bf16)acc[t][r];
                ps[r] = fmaf(acc[t][r], asv[t], ps[r]);
                pd[r] = fmaf(acc[t][r], adv[t], pd[r]);
            }
        }
#pragma unroll
        for (int r = 0; r < 4; ++r) {
#pragma unroll
            for (int d = 1; d < 16; d <<= 1) {
                ps[r] += __shfl_xor(ps[r], d, 64);
                pd[r] += __shfl_xor(pd[r], d, 64);
            }
        }
        if (row16 == 0) {
#pragma unroll
            for (int r = 0; r < 4; ++r) {
                int gm = nbase + wave * 16 + quad * 4 + r;
                if (gm < N) { as_[gm] = ps[r]; ad_[gm] = pd[r]; }
            }
        }
    }
}

// ---------------- bucketStart = excl-scan(bucketCount), 1 block ------------

__global__ __launch_bounds__(256) void bucket_scan(const int* __restrict__ bucketCount,
                                                   int* __restrict__ bucketStart,
                                                   int* __restrict__ offs,
                                                   int N, int E) {
    __shared__ int wsum[4];
    const int t = threadIdx.x;
    const int lane = t & 63;
    const int w = t >> 6;
    int v = bucketCount[t];
    int incl = wave_incl_scan(v, lane);
    if (lane == 63) wsum[w] = incl;
    __syncthreads();
    int pre = 0;
#pragma unroll
    for (int i = 0; i < 4; ++i) pre += (i < w) ? wsum[i] : 0;
    bucketStart[t] = incl - v + pre;
    if (t == 0) offs[N] = E;
}

// ---------------- per-bucket: offs + csr fill (LDS ranks) ------------------

__global__ __launch_bounds__(1024) void bucket_fill(const unsigned* __restrict__ ebuf,
                                                    const int* __restrict__ blockHist,
                                                    const int* __restrict__ bucketStart,
                                                    int* __restrict__ offs,
                                                    int* __restrict__ csr,
                                                    int N, int CB) {
    __shared__ int hist[512], excls[512], bhist_s[256], wsum[16];
    const int b = blockIdx.x;
    const int t = threadIdx.x;       // 0..1023
    const int lane = t & 63;
    const int w = t >> 6;            // 0..15
    const int gbase = bucketStart[b];

    if (t < 512) hist[t] = 0;
    if (t < 256) bhist_s[t] = blockHist[b * CBPAD + t];
    __syncthreads();

    // phase 1: node-degree histogram with register rank capture.
    // wave w handles chunks c = w, w+16, ... ; <=2 rounds of 64 per chunk.
    int rr[32];
#pragma unroll
    for (int ci = 0; ci < 16; ++ci) {
        int c = w + ci * 16;
        int cnt = (c < CB) ? bhist_s[c] : 0;
        const unsigned* __restrict__ ep = ebuf + ((size_t)b * CB + c) * ECAP;
#pragma unroll
        for (int ri = 0; ri < 2; ++ri) {
            int idx = ri * 64 + lane;
            if (idx < cnt) {
                unsigned rec = ep[idx];
                rr[ci * 2 + ri] = atomicAdd(&hist[rec & (BSIZE - 1)], 1);
            }
        }
    }
    __syncthreads();

    // phase 2: 512-entry exclusive scan (waves 0..7) -> offs
    int hv = (t < 512) ? hist[t] : 0;
    int incl = wave_incl_scan(hv, lane);
    if (lane == 63 && w < 8) wsum[w] = incl;
    __syncthreads();
    if (t < 512) {
        int pre = 0;
#pragma unroll
        for (int i = 0; i < 8; ++i) pre += (i < w) ? wsum[i] : 0;
        int excl = incl - hv + pre;
        int n = b * BSIZE + t;
        if (n < N) offs[n] = gbase + excl;
        excls[t] = excl;
    }
    __syncthreads();

    // phase 3: write csr (re-read ebuf region, L2-hot)
#pragma unroll
    for (int ci = 0; ci < 16; ++ci) {
        int c = w + ci * 16;
        int cnt = (c < CB) ? bhist_s[c] : 0;
        const unsigned* __restrict__ ep = ebuf + ((size_t)b * CB + c) * ECAP;
#pragma unroll
        for (int ri = 0; ri < 2; ++ri) {
            int idx = ri * 64 + lane;
            if (idx < cnt) {
                unsigned rec = ep[idx];
                csr[gbase + excls[rec & (BSIZE - 1)] + rr[ci * 2 + ri]] =
                    (int)(rec >> BSHIFT);
            }
        }
    }
}

// ---------------- MFMA GEMM layer-2 (K=64, bf16 A, 2-term) ----------------

__global__ __launch_bounds__(256) void gemm_mfma2(const __bf16* __restrict__ X,
                                                  const float* __restrict__ W,
                                                  const float* __restrict__ a_src,
                                                  const float* __restrict__ a_dst,
                                                  __bf16* __restrict__ Hout,
                                                  float* __restrict__ as_,
                                                  float* __restrict__ ad_,
                                                  int N, int nTiles) {
    constexpr int K = 64;
    __shared__ __bf16 Whi[64][K + 8];
    __shared__ __bf16 Wlo[64][K + 8];
    for (int idx = threadIdx.x; idx < K * 64; idx += 256) {
        int k = idx >> 6, n = idx & 63;
        float w = W[idx];
        __bf16 hi = (__bf16)w;
        Whi[n][k] = hi;
        Wlo[n][k] = (__bf16)(w - (float)hi);
    }
    __syncthreads();

    const int lane  = threadIdx.x & 63;
    const int wave  = threadIdx.x >> 6;
    const int row16 = lane & 15;
    const int quad  = lane >> 4;

    float asv[4], adv[4];
#pragma unroll
    for (int t = 0; t < 4; ++t) {
        asv[t] = a_src[t * 16 + row16];
        adv[t] = a_dst[t * 16 + row16];
    }

    for (int tile = blockIdx.x; tile < nTiles; tile += gridDim.x) {
        const int nbase = tile * 64;
        int gn = nbase + wave * 16 + row16;
        if (gn >= N) gn = N - 1;
        const __bf16* __restrict__ xp = X + (size_t)gn * K + quad * 8;
        bf16x8 a0 = *(const bf16x8*)(xp);
        bf16x8 a1 = *(const bf16x8*)(xp + 32);

        f32x4 acc[4] = {{0.f, 0.f, 0.f, 0.f}, {0.f, 0.f, 0.f, 0.f},
                        {0.f, 0.f, 0.f, 0.f}, {0.f, 0.f, 0.f, 0.f}};
#pragma unroll
        for (int kc = 0; kc < K; kc += 32) {
            bf16x8 a = (kc == 0) ? a0 : a1;
#pragma unroll
            for (int t = 0; t < 4; ++t) {
                bf16x8 bhi = *(const bf16x8*)&Whi[t * 16 + row16][kc + quad * 8];
                bf16x8 blo = *(const bf16x8*)&Wlo[t * 16 + row16][kc + quad * 8];
                acc[t] = __builtin_amdgcn_mfma_f32_16x16x32_bf16(a, bhi, acc[t], 0, 0, 0);
                acc[t] = __builtin_amdgcn_mfma_f32_16x16x32_bf16(a, blo, acc[t], 0, 0, 0);
            }
        }

        float ps[4] = {0.f, 0.f, 0.f, 0.f};
        float pd[4] = {0.f, 0.f, 0.f, 0.f};
#pragma unroll
        for (int t = 0; t < 4; ++t) {
#pragma unroll
            for (int r = 0; r < 4; ++r) {
                int gm = nbase + wave * 16 + quad * 4 + r;
                if (gm < N) Hout[(size_t)gm * 64 + t * 16 + row16] = (__bf16)acc[t][r];
                ps[r] = fmaf(acc[t][r], asv[t], ps[r]);
                pd[r] = fmaf(acc[t][r], adv[t], pd[r]);
            }
        }
#pragma unroll
        for (int r = 0; r < 4; ++r) {
#pragma unroll
            for (int d = 1; d < 16; d <<= 1) {
                ps[r] += __shfl_xor(ps[r], d, 64);
                pd[r] += __shfl_xor(pd[r], d, 64);
            }
        }
        if (row16 == 0) {
#pragma unroll
            for (int r = 0; r < 4; ++r) {
                int gm = nbase + wave * 16 + quad * 4 + r;
                if (gm < N) { as_[gm] = ps[r]; ad_[gm] = pd[r]; }
            }
        }
    }
}

// ---------------- fused segment softmax + aggregation (8x8, bf16x8) --------

__global__ __launch_bounds__(256) void gat_agg(const __bf16* __restrict__ h,
                                               const float* __restrict__ as_,
                                               const float* __restrict__ ad_,
                                               const float* __restrict__ bias,
                                               const int* __restrict__ offs,
                                               const int* __restrict__ csr,
                                               __bf16* __restrict__ out,
                                               int N, int do_relu) {
    int gtid = blockIdx.x * blockDim.x + threadIdx.x;
    int n = __builtin_amdgcn_readfirstlane(gtid >> 6);
    if (n >= N) return;
    const int lane = threadIdx.x & 63;
    const int g  = lane >> 3;   // edge group 0..7
    const int fl = lane & 7;    // feature octet index

    int beg = offs[n], end = offs[n + 1];
    float adn = ad_[n];
    float p_self = __expf(lrelu(as_[n] + adn));

    float den = p_self;
    float a[8];
    {
        bf16x8 t = *(const bf16x8*)(h + (size_t)n * 64 + fl * 8);
        float m0 = (g == 0) ? p_self : 0.f;
#pragma unroll
        for (int k = 0; k < 8; ++k) a[k] = m0 * (float)t[k];
    }

    for (int c0 = beg; c0 < end; c0 += 64) {
        int cnt = end - c0;
        if (cnt > 64) cnt = 64;
        int   s_l = (lane < cnt) ? csr[c0 + lane] : 0;
        float p_l = (lane < cnt) ? __expf(lrelu(as_[s_l] + adn)) : 0.f;
        float csum = p_l;
#pragma unroll
        for (int d = 32; d; d >>= 1) csum += __shfl_xor(csum, d, 64);
        den += csum;

        // 8 edges per round, one per group; <=7 padded slots on last round
        int rounds = (cnt + 7) >> 3;
        for (int r = 0; r < rounds; ++r) {
            int j = r * 8 + g;
            float w = __shfl(p_l, j, 64);
            int   s = __shfl(s_l, j, 64);
            bf16x8 hv = *(const bf16x8*)(h + (size_t)s * 64 + fl * 8);
#pragma unroll
            for (int k = 0; k < 8; ++k) a[k] = fmaf(w, (float)hv[k], a[k]);
        }
    }

    // reduce over 8 edge groups (lane bits 3..5)
#pragma unroll
    for (int d = 8; d <= 32; d <<= 1) {
#pragma unroll
        for (int k = 0; k < 8; ++k) a[k] += __shfl_xor(a[k], d, 64);
    }
    if (g == 0) {
        float inv = 1.f / (den + 1e-16f);
        const float4 b40 = *(const float4*)(bias + fl * 8);
        const float4 b41 = *(const float4*)(bias + fl * 8 + 4);
        float bb[8] = {b40.x, b40.y, b40.z, b40.w, b41.x, b41.y, b41.z, b41.w};
        bf16x8 ov;
#pragma unroll
        for (int k = 0; k < 8; ++k) {
            float o = fmaf(a[k], inv, bb[k]);
            if (do_relu) o = fmaxf(o, 0.f);
            ov[k] = (__bf16)o;
        }
        *(bf16x8*)(out + (size_t)n * 64 + fl * 8) = ov;
    }
}

// ---------------- final linear (bf16 A, 2-term) + log_softmax --------------

__global__ __launch_bounds__(256) void final_lsm(const __bf16* __restrict__ h,
                                                 const float* __restrict__ Wl,
                                                 const float* __restrict__ bl,
                                                 float* __restrict__ out,
                                                 int N, int nTiles) {
    __shared__ __bf16 Whi[48][72];
    __shared__ __bf16 Wlo[48][72];
    __shared__ float bls[48];
    for (int idx = threadIdx.x; idx < 48 * 64; idx += 256) {
        int c = idx >> 6, k = idx & 63;
        float w = (c < 40) ? Wl[k * 40 + c] : 0.f;
        __bf16 hi = (__bf16)w;
        Whi[c][k] = hi;
        Wlo[c][k] = (__bf16)(w - (float)hi);
    }
    if (threadIdx.x < 48) bls[threadIdx.x] = (threadIdx.x < 40) ? bl[threadIdx.x] : 0.f;
    __syncthreads();

    const int lane  = threadIdx.x & 63;
    const int wave  = threadIdx.x >> 6;
    const int col16 = lane & 15;
    const int quad  = lane >> 4;

    for (int tile = blockIdx.x; tile < nTiles; tile += gridDim.x) {
        const int nbase = tile * 64;
        int gn = nbase + wave * 16 + col16;
        if (gn >= N) gn = N - 1;
        const __bf16* __restrict__ xp = h + (size_t)gn * 64 + quad * 8;
        bf16x8 a0 = *(const bf16x8*)(xp);
        bf16x8 a1 = *(const bf16x8*)(xp + 32);

        f32x4 acc[3] = {{0.f, 0.f, 0.f, 0.f}, {0.f, 0.f, 0.f, 0.f},
                        {0.f, 0.f, 0.f, 0.f}};
#pragma unroll
        for (int kc = 0; kc < 64; kc += 32) {
            bf16x8 a = (kc == 0) ? a0 : a1;
#pragma unroll
            for (int t = 0; t < 3; ++t) {
                bf16x8 bhi = *(const bf16x8*)&Whi[t * 16 + col16][kc + quad * 8];
                bf16x8 blo = *(const bf16x8*)&Wlo[t * 16 + col16][kc + quad * 8];
                acc[t] = __builtin_amdgcn_mfma_f32_16x16x32_bf16(a, bhi, acc[t], 0, 0, 0);
                acc[t] = __builtin_amdgcn_mfma_f32_16x16x32_bf16(a, blo, acc[t], 0, 0, 0);
            }
        }

#pragma unroll
        for (int r = 0; r < 4; ++r) {
            int gm = nbase + wave * 16 + quad * 4 + r;
            float l0 = acc[0][r] + bls[col16];
            float l1 = acc[1][r] + bls[16 + col16];
            float l2 = (col16 < 8) ? (acc[2][r] + bls[32 + col16]) : NEG_BIG;
            float mx = fmaxf(fmaxf(l0, l1), l2);
#pragma unroll
            for (int d = 1; d < 16; d <<= 1) mx = fmaxf(mx, __shfl_xor(mx, d, 64));
            float s = __expf(l0 - mx) + __expf(l1 - mx) +
                      ((col16 < 8) ? __expf(l2 - mx) : 0.f);
#pragma unroll
            for (int d = 1; d < 16; d <<= 1) s += __shfl_xor(s, d, 64);
            float lse = mx + __logf(s);
            if (gm < N) {
                out[(size_t)gm * 40 + col16]      = l0 - lse;
                out[(size_t)gm * 40 + 16 + col16] = l1 - lse;
                if (col16 < 8) out[(size_t)gm * 40 + 32 + col16] = l2 - lse;
            }
        }
    }
}

// ---------------- launch ----------------

extern "C" void kernel_launch(void* const* d_in, const int* in_sizes, int n_in,
                              void* d_out, int out_size, void* d_ws, size_t ws_size,
                              hipStream_t stream) {
    const float* x      = (const float*)d_in[0];
    const int*   ei     = (const int*)d_in[1];
    const float* W1     = (const float*)d_in[2];
    const float* a_src1 = (const float*)d_in[3];
    const float* a_dst1 = (const float*)d_in[4];
    const float* b1     = (const float*)d_in[5];
    const float* W2     = (const float*)d_in[6];
    const float* a_src2 = (const float*)d_in[7];
    const float* a_dst2 = (const float*)d_in[8];
    const float* b2     = (const float*)d_in[9];
    const float* Wl     = (const float*)d_in[10];
    const float* bl     = (const float*)d_in[11];

    const int N = in_sizes[0] / 128;
    const int E = in_sizes[1] / 2;
    const int* src = ei;
    const int* dst = ei + E;
    const int nbuck = (N + BSIZE - 1) >> BSHIFT;
    const int CB = (E + CEPB - 1) / CEPB;   // must be <= 256

    char* p = (char*)d_ws;
    auto alloc = [&](size_t bytes) -> void* {
        void* r = (void*)p;
        p += (bytes + 255) & ~(size_t)255;
        return r;
    };
    int*      offs        = (int*)alloc((size_t)(N + 1) * 4);
    int*      bucketCount = (int*)alloc(256 * 4);
    int*      bucketStart = (int*)alloc(256 * 4);
    int*      blockHist   = (int*)alloc(256 * CBPAD * 4);
    unsigned* ebuf        = (unsigned*)alloc((size_t)nbuck * CB * ECAP * 4);
    int*      csr         = (int*)alloc((size_t)E * 4);
    __bf16*   hbf         = (__bf16*)alloc((size_t)N * 64 * 2);  // gemm h out
    __bf16*   habg        = (__bf16*)alloc((size_t)N * 64 * 2);  // agg out
    float*    as_         = (float*)alloc((size_t)N * 4);
    float*    ad_         = (float*)alloc((size_t)N * 4);

    hipMemsetAsync(bucketCount, 0, 256 * 4, stream);

    const int nTiles = (N + 63) / 64;
    int aggBlocks = (N * 64 + 255) / 256;

    fused_hist_gemm<<<CB + 1024, 256, 0, stream>>>(
        src, dst, bucketCount, blockHist, ebuf, E, CB,
        x, W1, a_src1, a_dst1, hbf, as_, ad_, N, nTiles);
    bucket_scan<<<1, 256, 0, stream>>>(bucketCount, bucketStart, offs, N, E);
    bucket_fill<<<nbuck, 1024, 0, stream>>>(ebuf, blockHist, bucketStart,
                                            offs, csr, N, CB);
    gat_agg<<<aggBlocks, 256, 0, stream>>>(hbf, as_, ad_, b1, offs, csr, habg, N, 1);
    gemm_mfma2<<<1024, 256, 0, stream>>>(habg, W2, a_src2, a_dst2, hbf, as_, ad_, N, nTiles);
    gat_agg<<<aggBlocks, 256, 0, stream>>>(hbf, as_, ad_, b2, offs, csr, habg, N, 0);
    final_lsm<<<nTiles, 256, 0, stream>>>(habg, Wl, bl, (float*)d_out, N, nTiles);
}

// Round 6
// 278.947 us; speedup vs baseline: 1.0494x; 1.0494x over previous
//
#include <hip/hip_runtime.h>
#include <math.h>

// ---------------------------------------------------------------------------
// GAT x2 + linear + log_softmax on MI355X. R17.
//   - R16 post-mortem: 8x8 gat_agg lost 4-deep load pipelining (1 gather in
//     flight, runtime-bounded loop = no unroll) -> latency-bound regression.
//     Lesson: loads-in-flight > instruction count for gather kernels.
//   - R17 gat_agg: back to 4x16 bf16x4 (R15-proven) with EIGHT independent
//     gathers in flight per iteration (static w[8]/s[8]/hv[8], full unroll;
//     ~50 VGPR, under the 64-VGPR occupancy cliff). Shuffle s[] first, issue
//     all 8 loads, shuffle w[] under load shadow, then fma.
//   - bucket_scan kernel deleted; gbase folded into bucket_fill as in-block
//     reduction over bucketCount[0..b-1] (one fewer serialized launch).
//   - R15 slotted-ebuf CSR build + fused gemm1 + gemm2/final unchanged.
// ---------------------------------------------------------------------------

#define NEG_SLOPE 0.2f
#define NEG_BIG -3.0e38f

#define BSHIFT 9
#define BSIZE 512            // nodes per bucket
#define CEPB 8192            // edges per chunk block
#define ECAP 112             // ebuf records per (bucket,chunk) slot
#define CBPAD 256            // blockHist row stride

typedef __bf16 bf16x8 __attribute__((ext_vector_type(8)));
typedef __bf16 bf16x4 __attribute__((ext_vector_type(4)));
typedef float f32x4 __attribute__((ext_vector_type(4)));

__device__ __forceinline__ float lrelu(float x) {
    return x >= 0.f ? x : NEG_SLOPE * x;
}

__device__ __forceinline__ int wave_incl_scan(int v, int lane) {
#pragma unroll
    for (int d = 1; d < 64; d <<= 1) {
        int t = __shfl_up(v, d, 64);
        if (lane >= d) v += t;
    }
    return v;
}

// ---------------- fused: hist+place || gemm1 (K=128, fp32 A hi/lo) ---------

__global__ __launch_bounds__(256) void fused_hist_gemm(
        const int* __restrict__ src, const int* __restrict__ dst,
        int* __restrict__ bucketCount, int* __restrict__ blockHist,
        unsigned* __restrict__ ebuf, int E, int CB,
        const float* __restrict__ X, const float* __restrict__ W,
        const float* __restrict__ a_src, const float* __restrict__ a_dst,
        __bf16* __restrict__ Hout, float* __restrict__ as_, float* __restrict__ ad_,
        int N, int nTiles) {
    constexpr int K = 128;
    __shared__ __bf16 Whi[64][K + 8];
    __shared__ __bf16 Wlo[64][K + 8];
    __shared__ int hist[256];

    if (blockIdx.x < (unsigned)CB) {
        // ---- hist+place path: LDS rank capture, direct slotted ebuf write --
        const int t = threadIdx.x;
        hist[t] = 0;
        __syncthreads();
        const int c = blockIdx.x;
        const int e0 = c * CEPB;
        const int e1 = min(e0 + CEPB, E);
        int rr[CEPB / 256];
#pragma unroll
        for (int i = 0; i < CEPB / 256; ++i) {
            int e = e0 + i * 256 + t;
            if (e < e1) rr[i] = atomicAdd(&hist[dst[e] >> BSHIFT], 1);
        }
        __syncthreads();
        int hv = hist[t];
        blockHist[t * CBPAD + c] = hv;                    // plain store
        if (hv > 0) atomicAdd(&bucketCount[t], hv);       // fire-and-forget
#pragma unroll
        for (int i = 0; i < CEPB / 256; ++i) {
            int e = e0 + i * 256 + t;
            if (e < e1) {
                int d = dst[e];                            // L1/L2 hot
                int b = d >> BSHIFT;
                ebuf[((size_t)b * CB + c) * ECAP + rr[i]] =
                    ((unsigned)src[e] << BSHIFT) | (unsigned)(d & (BSIZE - 1));
            }
        }
        return;
    }

    // ---- gemm path ----
    const int gbid = blockIdx.x - CB;
    for (int idx = threadIdx.x; idx < K * 64; idx += 256) {
        int k = idx >> 6, n = idx & 63;
        float w = W[idx];
        __bf16 hi = (__bf16)w;
        Whi[n][k] = hi;
        Wlo[n][k] = (__bf16)(w - (float)hi);
    }
    __syncthreads();

    const int lane  = threadIdx.x & 63;
    const int wave  = threadIdx.x >> 6;
    const int row16 = lane & 15;
    const int quad  = lane >> 4;

    float asv[4], adv[4];
#pragma unroll
    for (int t = 0; t < 4; ++t) {
        asv[t] = a_src[t * 16 + row16];
        adv[t] = a_dst[t * 16 + row16];
    }

    for (int tile = gbid; tile < nTiles; tile += 1024) {
        const int nbase = tile * 64;
        int gn = nbase + wave * 16 + row16;
        if (gn >= N) gn = N - 1;
        const float* __restrict__ xp = X + (size_t)gn * K + quad * 8;

        float4 xv[K / 16];
#pragma unroll
        for (int c = 0; c < K / 32; ++c) {
            xv[2 * c]     = *(const float4*)(xp + c * 32);
            xv[2 * c + 1] = *(const float4*)(xp + c * 32 + 4);
        }

        f32x4 acc[4] = {{0.f, 0.f, 0.f, 0.f}, {0.f, 0.f, 0.f, 0.f},
                        {0.f, 0.f, 0.f, 0.f}, {0.f, 0.f, 0.f, 0.f}};
#pragma unroll
        for (int kc = 0; kc < K; kc += 32) {
            float xs[8];
            *(float4*)&xs[0] = xv[kc / 16];
            *(float4*)&xs[4] = xv[kc / 16 + 1];
            bf16x8 ahi, alo;
#pragma unroll
            for (int j = 0; j < 8; ++j) {
                __bf16 hi = (__bf16)xs[j];
                ahi[j] = hi;
                alo[j] = (__bf16)(xs[j] - (float)hi);
            }
#pragma unroll
            for (int t = 0; t < 4; ++t) {
                bf16x8 bhi = *(const bf16x8*)&Whi[t * 16 + row16][kc + quad * 8];
                bf16x8 blo = *(const bf16x8*)&Wlo[t * 16 + row16][kc + quad * 8];
                acc[t] = __builtin_amdgcn_mfma_f32_16x16x32_bf16(ahi, bhi, acc[t], 0, 0, 0);
                acc[t] = __builtin_amdgcn_mfma_f32_16x16x32_bf16(ahi, blo, acc[t], 0, 0, 0);
                acc[t] = __builtin_amdgcn_mfma_f32_16x16x32_bf16(alo, bhi, acc[t], 0, 0, 0);
            }
        }

        float ps[4] = {0.f, 0.f, 0.f, 0.f};
        float pd[4] = {0.f, 0.f, 0.f, 0.f};
#pragma unroll
        for (int t = 0; t < 4; ++t) {
#pragma unroll
            for (int r = 0; r < 4; ++r) {
                int gm = nbase + wave * 16 + quad * 4 + r;
                if (gm < N) Hout[(size_t)gm * 64 + t * 16 + row16] = (__bf16)acc[t][r];
                ps[r] = fmaf(acc[t][r], asv[t], ps[r]);
                pd[r] = fmaf(acc[t][r], adv[t], pd[r]);
            }
        }
#pragma unroll
        for (int r = 0; r < 4; ++r) {
#pragma unroll
            for (int d = 1; d < 16; d <<= 1) {
                ps[r] += __shfl_xor(ps[r], d, 64);
                pd[r] += __shfl_xor(pd[r], d, 64);
            }
        }
        if (row16 == 0) {
#pragma unroll
            for (int r = 0; r < 4; ++r) {
                int gm = nbase + wave * 16 + quad * 4 + r;
                if (gm < N) { as_[gm] = ps[r]; ad_[gm] = pd[r]; }
            }
        }
    }
}

// ---------------- per-bucket: gbase + offs + csr fill (LDS ranks) ----------

__global__ __launch_bounds__(1024) void bucket_fill(const unsigned* __restrict__ ebuf,
                                                    const int* __restrict__ blockHist,
                                                    const int* __restrict__ bucketCount,
                                                    int* __restrict__ offs,
                                                    int* __restrict__ csr,
                                                    int N, int E, int CB) {
    __shared__ int hist[512], excls[512], bhist_s[256], wsum[16], gsum[16];
    const int b = blockIdx.x;
    const int t = threadIdx.x;       // 0..1023
    const int lane = t & 63;
    const int w = t >> 6;            // 0..15

    // gbase = sum of bucketCount[0..b-1] (waves 0..3 carry data)
    int v = (t < 256 && t < b) ? bucketCount[t] : 0;
#pragma unroll
    for (int d = 32; d; d >>= 1) v += __shfl_xor(v, d, 64);
    if (lane == 0) gsum[w] = v;
    if (t < 512) hist[t] = 0;
    if (t < 256) bhist_s[t] = blockHist[b * CBPAD + t];
    if (b == 0 && t == 0) offs[N] = E;
    __syncthreads();
    int gbase = 0;
#pragma unroll
    for (int i = 0; i < 16; ++i) gbase += gsum[i];

    // phase 1: node-degree histogram with register rank capture.
    // wave w handles chunks c = w, w+16, ... ; <=2 rounds of 64 per chunk.
    int rr[32];
#pragma unroll
    for (int ci = 0; ci < 16; ++ci) {
        int c = w + ci * 16;
        int cnt = (c < CB) ? bhist_s[c] : 0;
        const unsigned* __restrict__ ep = ebuf + ((size_t)b * CB + c) * ECAP;
#pragma unroll
        for (int ri = 0; ri < 2; ++ri) {
            int idx = ri * 64 + lane;
            if (idx < cnt) {
                unsigned rec = ep[idx];
                rr[ci * 2 + ri] = atomicAdd(&hist[rec & (BSIZE - 1)], 1);
            }
        }
    }
    __syncthreads();

    // phase 2: 512-entry exclusive scan (waves 0..7) -> offs
    int hv = (t < 512) ? hist[t] : 0;
    int incl = wave_incl_scan(hv, lane);
    if (lane == 63 && w < 8) wsum[w] = incl;
    __syncthreads();
    if (t < 512) {
        int pre = 0;
#pragma unroll
        for (int i = 0; i < 8; ++i) pre += (i < w) ? wsum[i] : 0;
        int excl = incl - hv + pre;
        int n = b * BSIZE + t;
        if (n < N) offs[n] = gbase + excl;
        excls[t] = excl;
    }
    __syncthreads();

    // phase 3: write csr (re-read ebuf region, L2-hot)
#pragma unroll
    for (int ci = 0; ci < 16; ++ci) {
        int c = w + ci * 16;
        int cnt = (c < CB) ? bhist_s[c] : 0;
        const unsigned* __restrict__ ep = ebuf + ((size_t)b * CB + c) * ECAP;
#pragma unroll
        for (int ri = 0; ri < 2; ++ri) {
            int idx = ri * 64 + lane;
            if (idx < cnt) {
                unsigned rec = ep[idx];
                csr[gbase + excls[rec & (BSIZE - 1)] + rr[ci * 2 + ri]] =
                    (int)(rec >> BSHIFT);
            }
        }
    }
}

// ---------------- MFMA GEMM layer-2 (K=64, bf16 A, 2-term) ----------------

__global__ __launch_bounds__(256) void gemm_mfma2(const __bf16* __restrict__ X,
                                                  const float* __restrict__ W,
                                                  const float* __restrict__ a_src,
                                                  const float* __restrict__ a_dst,
                                                  __bf16* __restrict__ Hout,
                                                  float* __restrict__ as_,
                                                  float* __restrict__ ad_,
                                                  int N, int nTiles) {
    constexpr int K = 64;
    __shared__ __bf16 Whi[64][K + 8];
    __shared__ __bf16 Wlo[64][K + 8];
    for (int idx = threadIdx.x; idx < K * 64; idx += 256) {
        int k = idx >> 6, n = idx & 63;
        float w = W[idx];
        __bf16 hi = (__bf16)w;
        Whi[n][k] = hi;
        Wlo[n][k] = (__bf16)(w - (float)hi);
    }
    __syncthreads();

    const int lane  = threadIdx.x & 63;
    const int wave  = threadIdx.x >> 6;
    const int row16 = lane & 15;
    const int quad  = lane >> 4;

    float asv[4], adv[4];
#pragma unroll
    for (int t = 0; t < 4; ++t) {
        asv[t] = a_src[t * 16 + row16];
        adv[t] = a_dst[t * 16 + row16];
    }

    for (int tile = blockIdx.x; tile < nTiles; tile += gridDim.x) {
        const int nbase = tile * 64;
        int gn = nbase + wave * 16 + row16;
        if (gn >= N) gn = N - 1;
        const __bf16* __restrict__ xp = X + (size_t)gn * K + quad * 8;
        bf16x8 a0 = *(const bf16x8*)(xp);
        bf16x8 a1 = *(const bf16x8*)(xp + 32);

        f32x4 acc[4] = {{0.f, 0.f, 0.f, 0.f}, {0.f, 0.f, 0.f, 0.f},
                        {0.f, 0.f, 0.f, 0.f}, {0.f, 0.f, 0.f, 0.f}};
#pragma unroll
        for (int kc = 0; kc < K; kc += 32) {
            bf16x8 a = (kc == 0) ? a0 : a1;
#pragma unroll
            for (int t = 0; t < 4; ++t) {
                bf16x8 bhi = *(const bf16x8*)&Whi[t * 16 + row16][kc + quad * 8];
                bf16x8 blo = *(const bf16x8*)&Wlo[t * 16 + row16][kc + quad * 8];
                acc[t] = __builtin_amdgcn_mfma_f32_16x16x32_bf16(a, bhi, acc[t], 0, 0, 0);
                acc[t] = __builtin_amdgcn_mfma_f32_16x16x32_bf16(a, blo, acc[t], 0, 0, 0);
            }
        }

        float ps[4] = {0.f, 0.f, 0.f, 0.f};
        float pd[4] = {0.f, 0.f, 0.f, 0.f};
#pragma unroll
        for (int t = 0; t < 4; ++t) {
#pragma unroll
            for (int r = 0; r < 4; ++r) {
                int gm = nbase + wave * 16 + quad * 4 + r;
                if (gm < N) Hout[(size_t)gm * 64 + t * 16 + row16] = (__bf16)acc[t][r];
                ps[r] = fmaf(acc[t][r], asv[t], ps[r]);
                pd[r] = fmaf(acc[t][r], adv[t], pd[r]);
            }
        }
#pragma unroll
        for (int r = 0; r < 4; ++r) {
#pragma unroll
            for (int d = 1; d < 16; d <<= 1) {
                ps[r] += __shfl_xor(ps[r], d, 64);
                pd[r] += __shfl_xor(pd[r], d, 64);
            }
        }
        if (row16 == 0) {
#pragma unroll
            for (int r = 0; r < 4; ++r) {
                int gm = nbase + wave * 16 + quad * 4 + r;
                if (gm < N) { as_[gm] = ps[r]; ad_[gm] = pd[r]; }
            }
        }
    }
}

// ------------- fused segment softmax + aggregation (4x16, 8-deep MLP) ------

__global__ __launch_bounds__(256) void gat_agg(const __bf16* __restrict__ h,
                                               const float* __restrict__ as_,
                                               const float* __restrict__ ad_,
                                               const float* __restrict__ bias,
                                               const int* __restrict__ offs,
                                               const int* __restrict__ csr,
                                               __bf16* __restrict__ out,
                                               int N, int do_relu) {
    int gtid = blockIdx.x * blockDim.x + threadIdx.x;
    int n = __builtin_amdgcn_readfirstlane(gtid >> 6);
    if (n >= N) return;
    const int lane = threadIdx.x & 63;
    const int g  = lane >> 4;   // edge group 0..3
    const int fl = lane & 15;   // feature quad index

    int beg = offs[n], end = offs[n + 1];
    float adn = ad_[n];
    float p_self = __expf(lrelu(as_[n] + adn));

    float den = p_self;
    float ax, ay, az, aw;
    {
        bf16x4 t = *(const bf16x4*)(h + (size_t)n * 64 + fl * 4);
        float m0 = (g == 0) ? p_self : 0.f;
        ax = m0 * (float)t[0];
        ay = m0 * (float)t[1];
        az = m0 * (float)t[2];
        aw = m0 * (float)t[3];
    }

    for (int c0 = beg; c0 < end; c0 += 64) {
        int cnt = end - c0;
        if (cnt > 64) cnt = 64;
        int   s_l = (lane < cnt) ? csr[c0 + lane] : 0;
        float p_l = (lane < cnt) ? __expf(lrelu(as_[s_l] + adn)) : 0.f;
        float csum = p_l;
#pragma unroll
        for (int d = 32; d; d >>= 1) csum += __shfl_xor(csum, d, 64);
        den += csum;

        // 8 independent gathers in flight per iteration (32 edges).
        int rounds = (cnt + 3) >> 2;
        for (int r = 0; r < rounds; r += 8) {
            int s[8];
#pragma unroll
            for (int i = 0; i < 8; ++i) s[i] = __shfl(s_l, (r + i) * 4 + g, 64);
            bf16x4 hv[8];
#pragma unroll
            for (int i = 0; i < 8; ++i)
                hv[i] = *(const bf16x4*)(h + (size_t)s[i] * 64 + fl * 4);
            float w[8];
#pragma unroll
            for (int i = 0; i < 8; ++i) w[i] = __shfl(p_l, (r + i) * 4 + g, 64);
#pragma unroll
            for (int i = 0; i < 8; ++i) {
                ax = fmaf(w[i], (float)hv[i][0], ax);
                ay = fmaf(w[i], (float)hv[i][1], ay);
                az = fmaf(w[i], (float)hv[i][2], az);
                aw = fmaf(w[i], (float)hv[i][3], aw);
            }
        }
    }

#pragma unroll
    for (int d = 16; d <= 32; d <<= 1) {
        ax += __shfl_xor(ax, d, 64);
        ay += __shfl_xor(ay, d, 64);
        az += __shfl_xor(az, d, 64);
        aw += __shfl_xor(aw, d, 64);
    }
    if (g == 0) {
        float inv = 1.f / (den + 1e-16f);
        const float4 b4 = *(const float4*)(bias + fl * 4);
        bf16x4 ov;
        float o0 = fmaf(ax, inv, b4.x);
        float o1 = fmaf(ay, inv, b4.y);
        float o2 = fmaf(az, inv, b4.z);
        float o3 = fmaf(aw, inv, b4.w);
        if (do_relu) {
            o0 = fmaxf(o0, 0.f); o1 = fmaxf(o1, 0.f);
            o2 = fmaxf(o2, 0.f); o3 = fmaxf(o3, 0.f);
        }
        ov[0] = (__bf16)o0; ov[1] = (__bf16)o1;
        ov[2] = (__bf16)o2; ov[3] = (__bf16)o3;
        *(bf16x4*)(out + (size_t)n * 64 + fl * 4) = ov;
    }
}

// ---------------- final linear (bf16 A, 2-term) + log_softmax --------------

__global__ __launch_bounds__(256) void final_lsm(const __bf16* __restrict__ h,
                                                 const float* __restrict__ Wl,
                                                 const float* __restrict__ bl,
                                                 float* __restrict__ out,
                                                 int N, int nTiles) {
    __shared__ __bf16 Whi[48][72];
    __shared__ __bf16 Wlo[48][72];
    __shared__ float bls[48];
    for (int idx = threadIdx.x; idx < 48 * 64; idx += 256) {
        int c = idx >> 6, k = idx & 63;
        float w = (c < 40) ? Wl[k * 40 + c] : 0.f;
        __bf16 hi = (__bf16)w;
        Whi[c][k] = hi;
        Wlo[c][k] = (__bf16)(w - (float)hi);
    }
    if (threadIdx.x < 48) bls[threadIdx.x] = (threadIdx.x < 40) ? bl[threadIdx.x] : 0.f;
    __syncthreads();

    const int lane  = threadIdx.x & 63;
    const int wave  = threadIdx.x >> 6;
    const int col16 = lane & 15;
    const int quad  = lane >> 4;

    for (int tile = blockIdx.x; tile < nTiles; tile += gridDim.x) {
        const int nbase = tile * 64;
        int gn = nbase + wave * 16 + col16;
        if (gn >= N) gn = N - 1;
        const __bf16* __restrict__ xp = h + (size_t)gn * 64 + quad * 8;
        bf16x8 a0 = *(const bf16x8*)(xp);
        bf16x8 a1 = *(const bf16x8*)(xp + 32);

        f32x4 acc[3] = {{0.f, 0.f, 0.f, 0.f}, {0.f, 0.f, 0.f, 0.f},
                        {0.f, 0.f, 0.f, 0.f}};
#pragma unroll
        for (int kc = 0; kc < 64; kc += 32) {
            bf16x8 a = (kc == 0) ? a0 : a1;
#pragma unroll
            for (int t = 0; t < 3; ++t) {
                bf16x8 bhi = *(const bf16x8*)&Whi[t * 16 + col16][kc + quad * 8];
                bf16x8 blo = *(const bf16x8*)&Wlo[t * 16 + col16][kc + quad * 8];
                acc[t] = __builtin_amdgcn_mfma_f32_16x16x32_bf16(a, bhi, acc[t], 0, 0, 0);
                acc[t] = __builtin_amdgcn_mfma_f32_16x16x32_bf16(a, blo, acc[t], 0, 0, 0);
            }
        }

#pragma unroll
        for (int r = 0; r < 4; ++r) {
            int gm = nbase + wave * 16 + quad * 4 + r;
            float l0 = acc[0][r] + bls[col16];
            float l1 = acc[1][r] + bls[16 + col16];
            float l2 = (col16 < 8) ? (acc[2][r] + bls[32 + col16]) : NEG_BIG;
            float mx = fmaxf(fmaxf(l0, l1), l2);
#pragma unroll
            for (int d = 1; d < 16; d <<= 1) mx = fmaxf(mx, __shfl_xor(mx, d, 64));
            float s = __expf(l0 - mx) + __expf(l1 - mx) +
                      ((col16 < 8) ? __expf(l2 - mx) : 0.f);
#pragma unroll
            for (int d = 1; d < 16; d <<= 1) s += __shfl_xor(s, d, 64);
            float lse = mx + __logf(s);
            if (gm < N) {
                out[(size_t)gm * 40 + col16]      = l0 - lse;
                out[(size_t)gm * 40 + 16 + col16] = l1 - lse;
                if (col16 < 8) out[(size_t)gm * 40 + 32 + col16] = l2 - lse;
            }
        }
    }
}

// ---------------- launch ----------------

extern "C" void kernel_launch(void* const* d_in, const int* in_sizes, int n_in,
                              void* d_out, int out_size, void* d_ws, size_t ws_size,
                              hipStream_t stream) {
    const float* x      = (const float*)d_in[0];
    const int*   ei     = (const int*)d_in[1];
    const float* W1     = (const float*)d_in[2];
    const float* a_src1 = (const float*)d_in[3];
    const float* a_dst1 = (const float*)d_in[4];
    const float* b1     = (const float*)d_in[5];
    const float* W2     = (const float*)d_in[6];
    const float* a_src2 = (const float*)d_in[7];
    const float* a_dst2 = (const float*)d_in[8];
    const float* b2     = (const float*)d_in[9];
    const float* Wl     = (const float*)d_in[10];
    const float* bl     = (const float*)d_in[11];

    const int N = in_sizes[0] / 128;
    const int E = in_sizes[1] / 2;
    const int* src = ei;
    const int* dst = ei + E;
    const int nbuck = (N + BSIZE - 1) >> BSHIFT;
    const int CB = (E + CEPB - 1) / CEPB;   // must be <= 256

    char* p = (char*)d_ws;
    auto alloc = [&](size_t bytes) -> void* {
        void* r = (void*)p;
        p += (bytes + 255) & ~(size_t)255;
        return r;
    };
    int*      offs        = (int*)alloc((size_t)(N + 1) * 4);
    int*      bucketCount = (int*)alloc(256 * 4);
    int*      blockHist   = (int*)alloc(256 * CBPAD * 4);
    unsigned* ebuf        = (unsigned*)alloc((size_t)nbuck * CB * ECAP * 4);
    int*      csr         = (int*)alloc((size_t)E * 4);
    __bf16*   hbf         = (__bf16*)alloc((size_t)N * 64 * 2);  // gemm h out
    __bf16*   habg        = (__bf16*)alloc((size_t)N * 64 * 2);  // agg out
    float*    as_         = (float*)alloc((size_t)N * 4);
    float*    ad_         = (float*)alloc((size_t)N * 4);

    hipMemsetAsync(bucketCount, 0, 256 * 4, stream);

    const int nTiles = (N + 63) / 64;
    int aggBlocks = (N * 64 + 255) / 256;

    fused_hist_gemm<<<CB + 1024, 256, 0, stream>>>(
        src, dst, bucketCount, blockHist, ebuf, E, CB,
        x, W1, a_src1, a_dst1, hbf, as_, ad_, N, nTiles);
    bucket_fill<<<nbuck, 1024, 0, stream>>>(ebuf, blockHist, bucketCount,
                                            offs, csr, N, E, CB);
    gat_agg<<<aggBlocks, 256, 0, stream>>>(hbf, as_, ad_, b1, offs, csr, habg, N, 1);
    gemm_mfma2<<<1024, 256, 0, stream>>>(habg, W2, a_src2, a_dst2, hbf, as_, ad_, N, nTiles);
    gat_agg<<<aggBlocks, 256, 0, stream>>>(hbf, as_, ad_, b2, offs, csr, habg, N, 0);
    final_lsm<<<nTiles, 256, 0, stream>>>(habg, Wl, bl, (float*)d_out, N, nTiles);
}